// Round 2
// 287.337 us; speedup vs baseline: 1.0505x; 1.0505x over previous
//
#include <hip/hip_runtime.h>
#include <cmath>

#define IMG_W 512
#define IMG_H 512
#define NIMG 64
#define OWV 502   // valid-conv output extent (SSIM branch)

struct KTaps {
    float kw[11];   // normalized gaussian, win=11, sigma=1.5 (SSIM)
    float ke[13];   // erf-gaussian, 13 taps, NOT normalized (L1)
};

// Zero-cost ordering pin for cross-lane LDS traffic within one wave:
// emits no instruction, but the compiler may not move memory ops across it.
// The per-wave DS pipe is in-order, so instruction order == LDS order.
#define WAVE_FENCE() __builtin_amdgcn_wave_barrier()

// ---------------- Kernel A: SSIM -> scalar sum ----------------
// Wave-autonomous: each wave owns 64 output cols and a private
// double-buffered LDS tile (76 staged cols). NO __syncthreads in the row
// loop -- waves drift out of phase so memory stalls interleave across the
// SIMD. Cross-lane LDS ordering is pinned by WAVE_FENCE() per iteration.
// Prefetch is one full row-iteration deep: row rr+2 is loaded at iter rr
// and LDS-written at iter rr+1.
__global__ __launch_bounds__(256) void ssim_band_kernel(
        const float* __restrict__ x, const float* __restrict__ y,
        double* __restrict__ ssum, KTaps kt) {
    __shared__ __align__(16) float sxw[4][2][80];   // per-wave, dbuf, 76 cols
    __shared__ __align__(16) float syw[4][2][80];

    const int img   = blockIdx.z;
    const int band  = blockIdx.y;     // 0..7
    const int strip = blockIdx.x;     // 0..1
    const int tid   = threadIdx.x;
    const int w     = tid >> 6;
    const int lane  = tid & 63;
    const int r0    = band * 64;
    const int wc0   = strip * 256 + w * 64;   // wave's first output col

    const float* __restrict__ xi = x + (size_t)img * IMG_H * IMG_W;
    const float* __restrict__ yi = y + (size_t)img * IMG_H * IMG_W;

    // staging roles: lanes 0..37 stage x (38 f2 = cols wc0..wc0+75),
    // lanes 26..63 stage y (lanes 26..37 do both). OOB cols load zeros.
    const bool xon  = (lane < 38);
    const bool yon  = (lane >= 26);
    const int  xcol = wc0 + 2 * lane;
    const int  ycol = wc0 + 2 * (lane - 26);
    const bool xok  = xon && (xcol < IMG_W);
    const bool yok  = yon && (ycol < IMG_W);

    auto ldx2 = [&](int r) -> float2 {
        float2 v = make_float2(0.f, 0.f);
        if (xok && r < IMG_H) v = *(const float2*)(xi + (size_t)r * IMG_W + xcol);
        return v;
    };
    auto ldy2 = [&](int r) -> float2 {
        float2 v = make_float2(0.f, 0.f);
        if (yok && r < IMG_H) v = *(const float2*)(yi + (size_t)r * IMG_W + ycol);
        return v;
    };

    // parity-resolved 12-tap weights (window read is f2-aligned from even base)
    float w12[12];
#pragma unroll
    for (int j = 0; j < 12; ++j) w12[j] = 0.f;
    if (lane & 1) {
#pragma unroll
        for (int j = 0; j < 11; ++j) w12[j + 1] = kt.kw[j];
    } else {
#pragma unroll
        for (int j = 0; j < 11; ++j) w12[j] = kt.kw[j];
    }

    float acc[11][5];
#pragma unroll
    for (int i = 0; i < 11; ++i)
#pragma unroll
        for (int q = 0; q < 5; ++q) acc[i][q] = 0.f;
    float tsum = 0.f;

    const int basei = lane & ~1;     // even LDS base of this lane's window
    const int outc  = wc0 + lane;

    // prologue: row r0 -> LDS[0]; prefetch row r0+1 -> regs
    {
        const float2 vx = ldx2(r0);
        const float2 vy = ldy2(r0);
        if (xon) *(float2*)&sxw[w][0][2 * lane] = vx;
        if (yon) *(float2*)&syw[w][0][2 * (lane - 26)] = vy;
    }
    float2 pfx = ldx2(r0 + 1);
    float2 pfy = ldy2(r0 + 1);
    WAVE_FENCE();   // prologue stage visible before first window read

#pragma unroll 1
    for (int chunk = 0; chunk < 7; ++chunk) {
#pragma unroll
        for (int p = 0; p < 11; ++p) {
            const int rr = chunk * 11 + p;
            if (rr <= 73) {
                const int b = rr & 1;
                // h-pass window reads (buffer b holds row rr)
                float xv[12], yv[12];
#pragma unroll
                for (int j = 0; j < 6; ++j) {
                    const float2 a = *(const float2*)&sxw[w][b][basei + 2 * j];
                    const float2 c = *(const float2*)&syw[w][b][basei + 2 * j];
                    xv[2 * j] = a.x; xv[2 * j + 1] = a.y;
                    yv[2 * j] = c.x; yv[2 * j + 1] = c.y;
                }
                // stage row rr+1 (loaded last iter) into the other buffer
                if (rr < 73) {
                    if (xon) *(float2*)&sxw[w][b ^ 1][2 * lane] = pfx;
                    if (yon) *(float2*)&syw[w][b ^ 1][2 * (lane - 26)] = pfy;
                }
                // issue load of row rr+2 (consumed at next iteration's stage)
                if (rr < 72) {
                    pfx = ldx2(r0 + rr + 2);
                    pfy = ldy2(r0 + rr + 2);
                }
                // fused h-pass: 12-value window, 5 quantities
                float h0 = 0.f, h1 = 0.f, h2 = 0.f, h3 = 0.f, h4 = 0.f;
#pragma unroll
                for (int j = 0; j < 12; ++j) {
                    const float wj = w12[j];
                    const float a = xv[j], bb = yv[j];
                    h0 += wj * a;
                    h1 += wj * bb;
                    h2 += wj * (a * a);
                    h3 += wj * (bb * bb);
                    h4 += wj * (a * bb);
                }
                // v-pass: 55 FMAs into mod-11 pending slots (static indices)
#pragma unroll
                for (int d = 0; d <= 10; ++d) {
                    const int s = (p + 11 - d) % 11;
                    const float wv = kt.kw[d];
                    acc[s][0] += wv * h0; acc[s][1] += wv * h1; acc[s][2] += wv * h2;
                    acc[s][3] += wv * h3; acc[s][4] += wv * h4;
                }
                {   // slot (p+1)%11 completed output row ro = rr-10
                    const int sc = (p + 1) % 11;
                    const int ro = rr - 10;
                    if (ro >= 0) {
                        const int o = r0 + ro;
                        if (o < OWV && outc < OWV) {
                            const float mx = acc[sc][0], my = acc[sc][1];
                            const float vx = acc[sc][2] - mx * mx;
                            const float vy = acc[sc][3] - my * my;
                            const float cov = acc[sc][4] - mx * my;
                            const float c1 = 1e-4f, c2 = 9e-4f;
                            tsum += ((2.f * mx * my + c1) * (2.f * cov + c2)) /
                                    ((mx * mx + my * my + c1) * (vx + vy + c2));
                        }
                    }
#pragma unroll
                    for (int q = 0; q < 5; ++q) acc[sc][q] = 0.f;   // ALWAYS reset
                }
                // pin ordering: reads(rr) before writes(rr+1), writes(rr)
                // before reads(rr+1). Zero-cost; VALU may still cross.
                WAVE_FENCE();
            }
        }
    }

    // reduce + one atomic per block (single real barrier in the kernel)
#pragma unroll
    for (int off = 32; off > 0; off >>= 1) tsum += __shfl_down(tsum, off, 64);
    __shared__ float wsum[4];
    if (lane == 0) wsum[w] = tsum;
    __syncthreads();
    if (tid == 0) atomicAdd(ssum, (double)(wsum[0] + wsum[1] + wsum[2] + wsum[3]));
}

// ---------------- Kernel B: L1 map + combine ----------------
// Wave-autonomous: each wave owns 128 output cols (2 per lane) and a
// private 140-col LDS tile (incl. 6+6 halo; halo cols OOB -> staged zeros).
// No s_barrier at all; WAVE_FENCE pins cross-lane LDS ordering.
__global__ __launch_bounds__(256) void l1_band_kernel(
        const float* __restrict__ x, const float* __restrict__ y,
        const double* __restrict__ ssum, float* __restrict__ out, KTaps kt) {
    __shared__ __align__(16) float sdw[4][2][144];   // per-wave, dbuf, 140 used

    const int img  = blockIdx.y;
    const int band = blockIdx.x;   // 0..15
    const int tid  = threadIdx.x;
    const int w    = tid >> 6;
    const int lane = tid & 63;
    const int o0   = band * 32;
    const int rin0 = o0 - 6;
    const int wc0  = w * 128;      // wave's first output col

    const float* __restrict__ xi = x + (size_t)img * IMG_H * IMG_W;
    const float* __restrict__ yi = y + (size_t)img * IMG_H * IMG_W;
    float* __restrict__ oi = out + (size_t)img * IMG_H * IMG_W;

    const float base = 100.f * 0.84f * (1.f - (float)(*ssum) * (1.f / 16128256.f));

    // staging: 70 f2 cover cols wc0-6 .. wc0+133 (local idx i = col-(wc0-6)).
    // lane l -> f2 #l (idx 2l); lanes 58..63 also f2 #(64+l-58) (idx 128+..).
    const int  g0  = wc0 - 6 + 2 * lane;
    const bool ok0 = (g0 >= 0) && (g0 < IMG_W);
    const bool on1 = (lane >= 58);
    const int  g1  = wc0 + 6 + 2 * lane;            // = wc0-6+2*(64+lane-58)
    const bool ok1 = on1 && (g1 < IMG_W);
    const int  i1  = 128 + 2 * (lane - 58);

    auto ldd = [&](int r, bool ok, int g) -> float2 {   // d = y-x, zero OOB
        float2 v = make_float2(0.f, 0.f);
        if (ok && r >= 0 && r < IMG_H) {
            const float2 a  = *(const float2*)(xi + (size_t)r * IMG_W + g);
            const float2 bb = *(const float2*)(yi + (size_t)r * IMG_W + g);
            v = make_float2(bb.x - a.x, bb.y - a.y);
        }
        return v;
    };

    float acc[13][2];
#pragma unroll
    for (int i = 0; i < 13; ++i) { acc[i][0] = 0.f; acc[i][1] = 0.f; }

    // prologue: row rin0 -> LDS[0]; prefetch row rin0+1 -> regs
    {
        const float2 v0 = ldd(rin0, ok0, g0);
        const float2 v1 = ldd(rin0, ok1, g1);
        *(float2*)&sdw[w][0][2 * lane] = v0;
        if (on1) *(float2*)&sdw[w][0][i1] = v1;
    }
    float2 pf0 = ldd(rin0 + 1, ok0, g0);
    float2 pf1 = ldd(rin0 + 1, ok1, g1);
    WAVE_FENCE();   // prologue stage visible before first window read

#pragma unroll 1
    for (int chunk = 0; chunk < 4; ++chunk) {
#pragma unroll
        for (int p = 0; p < 13; ++p) {
            const int rr = chunk * 13 + p;
            if (rr <= 43) {
                const int b = rr & 1;
                // h-pass: 14-value window serves both cols (window start = 2*lane)
                float dv[14];
#pragma unroll
                for (int j = 0; j < 7; ++j) {
                    const float2 a = *(const float2*)&sdw[w][b][2 * lane + 2 * j];
                    dv[2 * j] = a.x; dv[2 * j + 1] = a.y;
                }
                // stage row rr+1 into other buffer (zeros for OOB = zero-pad)
                if (rr < 43) {
                    *(float2*)&sdw[w][b ^ 1][2 * lane] = pf0;
                    if (on1) *(float2*)&sdw[w][b ^ 1][i1] = pf1;
                }
                // issue load of row rr+2
                if (rr < 42) {
                    pf0 = ldd(rin0 + rr + 2, ok0, g0);
                    pf1 = ldd(rin0 + rr + 2, ok1, g1);
                }
                float a0 = 0.f, a1 = 0.f;
#pragma unroll
                for (int u = 0; u < 13; ++u) {
                    a0 += kt.ke[u] * dv[u];
                    a1 += kt.ke[u] * dv[u + 1];
                }
                // v-pass into mod-13 pending slots
#pragma unroll
                for (int dd = 0; dd <= 12; ++dd) {
                    const int s = (p + 13 - dd) % 13;
                    acc[s][0] += kt.ke[dd] * a0;
                    acc[s][1] += kt.ke[dd] * a1;
                }
                {
                    const int sc = (p + 1) % 13;
                    const int ro = rr - 12;
                    if (ro >= 0) {
                        const int o = o0 + ro;   // always in [0,511]
                        *(float2*)&oi[(size_t)o * IMG_W + wc0 + 2 * lane] =
                            make_float2(base + 16.f * fabsf(acc[sc][0]),
                                        base + 16.f * fabsf(acc[sc][1]));
                    }
                    acc[sc][0] = 0.f; acc[sc][1] = 0.f;   // ALWAYS reset
                }
                WAVE_FENCE();   // pin cross-iteration LDS ordering, zero cost
            }
        }
    }
}

extern "C" void kernel_launch(void* const* d_in, const int* in_sizes, int n_in,
                              void* d_out, int out_size, void* d_ws, size_t ws_size,
                              hipStream_t stream) {
    const float* x = (const float*)d_in[0];
    const float* y = (const float*)d_in[1];
    float* out = (float*)d_out;
    double* ssum = (double*)d_ws;

    KTaps kt;
    {   // normalized gaussian win=11 sigma=1.5 (exp-based)
        double g[11], s = 0.0;
        for (int i = 0; i < 11; ++i) {
            const double d = (double)i - 5.0;
            g[i] = std::exp(-(d * d) / 4.5);
            s += g[i];
        }
        for (int i = 0; i < 11; ++i) kt.kw[i] = (float)(g[i] / s);
    }
    {   // erf-gaussian, tail=6 -> 13 taps, sigma=1.5, NOT normalized
        const double t = 0.70710678 / 1.5;
        for (int i = 0; i < 13; ++i) {
            const double xx = (double)i - 6.0;
            const double v = 0.5 * (std::erf(t * (xx + 0.5)) - std::erf(t * (xx - 0.5)));
            kt.ke[i] = (float)(v < 0.0 ? 0.0 : v);
        }
    }

    hipMemsetAsync(ssum, 0, sizeof(double), stream);

    ssim_band_kernel<<<dim3(2, 8, NIMG), dim3(256), 0, stream>>>(x, y, ssum, kt);
    l1_band_kernel<<<dim3(16, NIMG, 1), dim3(256), 0, stream>>>(x, y, ssum, out, kt);
}